// Round 2
// baseline (163.242 us; speedup 1.0000x reference)
//
#include <hip/hip_runtime.h>

#define IMG_H 512
#define IMG_W 512
#define N_IMG 24                          // B*C
#define NPIX (N_IMG * IMG_H * IMG_W)      // 6291456
#define ROWS_PT 4                         // rows per thread
#define NROWS 8                           // loaded rows per input
#define SLABS (IMG_H / ROWS_PT)           // 128
#define SCOLS (IMG_W / 4)                 // 128 strip-columns
#define BLOCK 256
#define NBLOCKS ((N_IMG * SLABS * SCOLS) / BLOCK)  // 1536

// Partial vmem wait + hard scheduler fence (keeps consumers below the wait).
#define VMWAIT(N)                                             \
    asm volatile("s_waitcnt vmcnt(" #N ")" ::: "memory");     \
    __builtin_amdgcn_sched_barrier(0)

// Branchless reflect for PAD=2: min(|x|, 2H-2-|x|)
__device__ __forceinline__ int reflect_b(int x) {
    int a = x < 0 ? -x : x;
    int b = 2 * IMG_H - 2 - a;
    return a < b ? a : b;
}

// Raw 16B load via volatile asm: no compiler waitcnt, immovable at IR level,
// program-ordered against the VMWAIT asms.
__device__ __forceinline__ float4 gload4(const float* p) {
    float4 r;
    asm volatile("global_load_dwordx4 %0, %1, off" : "=v"(r) : "v"(p));
    return r;
}

// Branchless fixup: raw A (cols aL..aL+3) / B (cols aR..aR+3) -> 8-float
// window (cols w0-2..w0+5, reflect-padded). Pure cndmask selects.
__device__ __forceinline__ void fix_row(float4 A, float4 B, int w0, float w[8]) {
    const bool e0 = (w0 == 0);
    const bool e5 = (w0 == 508);
    w[0] = e0 ? A.z : A.x;
    w[1] = A.y;
    w[2] = e0 ? A.x : A.z;
    w[3] = e0 ? A.y : A.w;
    w[4] = e0 ? A.z : (e5 ? B.z : B.x);
    w[5] = e0 ? A.w : (e5 ? B.w : B.y);
    w[6] = B.z;
    w[7] = e5 ? B.y : B.w;
}

// Wave-aggregate census compare: the final result is a sum over all lanes,
// so fold each comparison-slot across the wave NOW via ballot masks.
// Per element: 2 v_cmp (VALU) + s_xor_b64/s_bcnt1/s_add (SALU pipe) —
// replaces the per-lane 2 v_cmp + v_addc (3 VALU) formulation.
#define DO_ROW(R)                                                              \
    {                                                                          \
        const float pc0 = pw[(R) + 2][2], pc1 = pw[(R) + 2][3],                \
                    pc2 = pw[(R) + 2][4], pc3 = pw[(R) + 2][5];                \
        const float gc0 = gw[(R) + 2][2], gc1 = gw[(R) + 2][3],                \
                    gc2 = gw[(R) + 2][4], gc3 = gw[(R) + 2][5];                \
        _Pragma("unroll")                                                      \
        for (int dy = 0; dy < 5; ++dy) {                                       \
            const int row = (R) + dy;                                          \
            _Pragma("unroll")                                                  \
            for (int dx = 0; dx < 5; ++dx) {                                   \
                if (dy == 2 && dx == 2) continue;                              \
                scnt += (unsigned)__builtin_popcountll(                        \
                    __ballot(pw[row][0 + dx] < pc0) ^                          \
                    __ballot(gw[row][0 + dx] < gc0));                          \
                scnt += (unsigned)__builtin_popcountll(                        \
                    __ballot(pw[row][1 + dx] < pc1) ^                          \
                    __ballot(gw[row][1 + dx] < gc1));                          \
                scnt += (unsigned)__builtin_popcountll(                        \
                    __ballot(pw[row][2 + dx] < pc2) ^                          \
                    __ballot(gw[row][2 + dx] < gc2));                          \
                scnt += (unsigned)__builtin_popcountll(                        \
                    __ballot(pw[row][3 + dx] < pc3) ^                          \
                    __ballot(gw[row][3 + dx] < gc3));                          \
            }                                                                  \
        }                                                                      \
    }

__global__ __launch_bounds__(BLOCK, 2) void census_main(
    const float* __restrict__ pred, const float* __restrict__ gt,
    unsigned int* __restrict__ ws)
{
    const int t    = blockIdx.x * BLOCK + threadIdx.x;
    const int sc   = t & (SCOLS - 1);       // strip column (consecutive lanes)
    const int rest = t >> 7;
    const int slab = rest & (SLABS - 1);
    const int img  = rest >> 7;
    const int w0   = sc * 4;
    const int h0   = slab * ROWS_PT;

    const float* __restrict__ pimg = pred + (size_t)img * IMG_H * IMG_W;
    const float* __restrict__ gimg = gt   + (size_t)img * IMG_H * IMG_W;

    // Branchless clamped in-bounds addresses (aL in [0,506], aR in [2,508]).
    const int aL = max(0, min(w0 - 2, IMG_W - 6));
    const int aR = max(2, min(w0 + 2, IMG_W - 4));

    // ---- issue ALL 32 loads (4 per row: pA,pB,gA,gB), volatile order ----
    float4 pA[NROWS], pB[NROWS], gA[NROWS], gB[NROWS];
    #pragma unroll
    for (int i = 0; i < NROWS; ++i) {
        const int ry = reflect_b(h0 - 2 + i);
        const float* prow = pimg + ry * IMG_W;
        const float* grow = gimg + ry * IMG_W;
        pA[i] = gload4(prow + aL);
        pB[i] = gload4(prow + aR);
        gA[i] = gload4(grow + aL);
        gB[i] = gload4(grow + aR);
    }
    __builtin_amdgcn_sched_barrier(0);

    float pw[NROWS][8], gw[NROWS][8];
    unsigned int scnt = 0;   // wave-uniform accumulator (lives in SGPR)

    // rows 0,1 landed (loads 0..7 retired; <=24 outstanding)
    VMWAIT(24);
    fix_row(pA[0], pB[0], w0, pw[0]); fix_row(gA[0], gB[0], w0, gw[0]);
    fix_row(pA[1], pB[1], w0, pw[1]); fix_row(gA[1], gB[1], w0, gw[1]);

    // rows 2,3,4 landed (<=12 outstanding)
    VMWAIT(12);
    fix_row(pA[2], pB[2], w0, pw[2]); fix_row(gA[2], gB[2], w0, gw[2]);
    fix_row(pA[3], pB[3], w0, pw[3]); fix_row(gA[3], gB[3], w0, gw[3]);
    fix_row(pA[4], pB[4], w0, pw[4]); fix_row(gA[4], gB[4], w0, gw[4]);
    DO_ROW(0)            // rows 5..7 still in flight

    VMWAIT(8);
    fix_row(pA[5], pB[5], w0, pw[5]); fix_row(gA[5], gB[5], w0, gw[5]);
    DO_ROW(1)

    VMWAIT(4);
    fix_row(pA[6], pB[6], w0, pw[6]); fix_row(gA[6], gB[6], w0, gw[6]);
    DO_ROW(2)

    VMWAIT(0);
    fix_row(pA[7], pB[7], w0, pw[7]); fix_row(gA[7], gB[7], w0, gw[7]);
    DO_ROW(3)

    // ---- scnt is already the per-WAVE total (ballot folded the lanes) ----
    __shared__ unsigned int wave_sums[BLOCK / 64];
    const int lane = threadIdx.x & 63;
    const int wid  = threadIdx.x >> 6;
    if (lane == 0) wave_sums[wid] = scnt;
    __syncthreads();

    if (threadIdx.x == 0) {
        // One plain store per block to a distinct address: zero contention,
        // no fence, no readback. Wave retires immediately.
        ws[blockIdx.x] = wave_sums[0] + wave_sums[1] +
                         wave_sums[2] + wave_sums[3];
    }
}

// Second pass: one block sums the 1536 per-block partials and writes the mean.
// Kernel-boundary release/acquire makes census_main's stores visible here.
__global__ __launch_bounds__(BLOCK, 1) void census_reduce(
    const unsigned int* __restrict__ ws, float* __restrict__ out)
{
    unsigned int s = 0;
    #pragma unroll
    for (int i = 0; i < NBLOCKS / BLOCK; ++i)      // 6 iterations
        s += ws[threadIdx.x + i * BLOCK];

    #pragma unroll
    for (int off = 32; off > 0; off >>= 1)
        s += __shfl_down(s, off, 64);

    __shared__ unsigned int wsum[BLOCK / 64];
    const int lane = threadIdx.x & 63;
    const int wid  = threadIdx.x >> 6;
    if (lane == 0) wsum[wid] = s;
    __syncthreads();

    if (threadIdx.x == 0) {
        unsigned int tot = wsum[0] + wsum[1] + wsum[2] + wsum[3];
        out[0] = (float)((double)tot / (double)NPIX);
    }
}

extern "C" void kernel_launch(void* const* d_in, const int* in_sizes, int n_in,
                              void* d_out, int out_size, void* d_ws, size_t ws_size,
                              hipStream_t stream) {
    const float* pred = (const float*)d_in[0];
    const float* gt   = (const float*)d_in[1];
    float* out        = (float*)d_out;
    unsigned int* ws  = (unsigned int*)d_ws;   // needs NBLOCKS*4 = 6144 B

    census_main<<<NBLOCKS, BLOCK, 0, stream>>>(pred, gt, ws);
    census_reduce<<<1, BLOCK, 0, stream>>>(ws, out);
}

// Round 3
// 96.429 us; speedup vs baseline: 1.6929x; 1.6929x over previous
//
#include <hip/hip_runtime.h>

#define IMG_H 512
#define IMG_W 512
#define N_IMG 24                          // B*C
#define NPIX (N_IMG * IMG_H * IMG_W)      // 6291456
#define ROWS_PB 8                         // output rows per block
#define SROWS 12                          // staged rows = ROWS_PB + 4 halo
#define LDSW 520                          // 2 halo + 512 data + 2 halo + pad (16B-aligned stride)
#define RBLK (IMG_H / ROWS_PB)            // 64 row-blocks per image
#define BLOCK 256
#define NBLOCKS (N_IMG * RBLK)            // 1536

// Branchless reflect for PAD=2 rows: min(|x|, 2H-2-|x|)
__device__ __forceinline__ int reflect_b(int x) {
    int a = x < 0 ? -x : x;
    int b = 2 * IMG_H - 2 - a;
    return a < b ? a : b;
}

// Load one window row (8 floats per input) from LDS. Window col x lives at
// lds idx x+2, so the 8-wide window for output quad w0 starts at idx w0:
// byte offset = r*2080 + 16*sc  -> 16B-aligned ds_read_b128, lane stride 16B
// (contiguous across the wave: conflict-free).
#define ROW_LD(K)                                                      \
    {                                                                  \
        const int r_ = sl4 + (K);                                      \
        const float4 a_ = *(const float4*)&lds[0][r_][c4];             \
        const float4 b_ = *(const float4*)&lds[0][r_][c4 + 4];         \
        pw[K][0] = a_.x; pw[K][1] = a_.y; pw[K][2] = a_.z; pw[K][3] = a_.w; \
        pw[K][4] = b_.x; pw[K][5] = b_.y; pw[K][6] = b_.z; pw[K][7] = b_.w; \
        const float4 c_ = *(const float4*)&lds[1][r_][c4];             \
        const float4 d_ = *(const float4*)&lds[1][r_][c4 + 4];         \
        gw[K][0] = c_.x; gw[K][1] = c_.y; gw[K][2] = c_.z; gw[K][3] = c_.w; \
        gw[K][4] = d_.x; gw[K][5] = d_.y; gw[K][6] = d_.z; gw[K][7] = d_.w; \
    }

// Per-lane census compare (proven round-1 formulation: 2 v_cmp + addc).
#define DO_ROW(R)                                                              \
    {                                                                          \
        const float pc0 = pw[(R) + 2][2], pc1 = pw[(R) + 2][3],                \
                    pc2 = pw[(R) + 2][4], pc3 = pw[(R) + 2][5];                \
        const float gc0 = gw[(R) + 2][2], gc1 = gw[(R) + 2][3],                \
                    gc2 = gw[(R) + 2][4], gc3 = gw[(R) + 2][5];                \
        _Pragma("unroll")                                                      \
        for (int dy = 0; dy < 5; ++dy) {                                       \
            const int row = (R) + dy;                                          \
            _Pragma("unroll")                                                  \
            for (int dx = 0; dx < 5; ++dx) {                                   \
                if (dy == 2 && dx == 2) continue;                              \
                c0 += (int)((pw[row][0 + dx] < pc0) != (gw[row][0 + dx] < gc0)); \
                c1 += (int)((pw[row][1 + dx] < pc1) != (gw[row][1 + dx] < gc1)); \
                c2 += (int)((pw[row][2 + dx] < pc2) != (gw[row][2 + dx] < gc2)); \
                c3 += (int)((pw[row][3 + dx] < pc3) != (gw[row][3 + dx] < gc3)); \
            }                                                                  \
        }                                                                      \
    }

__global__ __launch_bounds__(BLOCK, 3) void census_main(
    const float* __restrict__ pred, const float* __restrict__ gt,
    unsigned int* __restrict__ ws)
{
    // XCD-chunked swizzle: consecutive logical blocks (vertically adjacent
    // tiles sharing 4 halo rows) land on the same XCD's L2. 1536 % 8 == 0.
    const int b   = blockIdx.x;
    const int n   = (b & 7) * (NBLOCKS / 8) + (b >> 3);
    const int img = n >> 6;                 // n / RBLK
    const int rb  = n & (RBLK - 1);
    const int h0  = rb * ROWS_PB;

    const float* __restrict__ pimg = pred + (size_t)img * IMG_H * IMG_W;
    const float* __restrict__ gimg = gt   + (size_t)img * IMG_H * IMG_W;

    // LDS tile: [input][staged row][2 halo | 512 data | 2 halo | 4 pad]
    __shared__ float lds[2][SROWS][LDSW];   // 49,920 B -> 3 blocks/CU

    // ---- cooperative staging: 12 rows x 512 cols x 2 inputs ----
    // thread -> (col quad q, row group rg); 6 rows each, fully coalesced.
    {
        const int q  = threadIdx.x & 127;
        const int rg = threadIdx.x >> 7;
        #pragma unroll
        for (int i = 0; i < 6; ++i) {
            const int lr = rg + 2 * i;
            const int gy = reflect_b(h0 - 2 + lr);
            const float4 pv = *(const float4*)(pimg + (size_t)gy * IMG_W + 4 * q);
            const float4 gv = *(const float4*)(gimg + (size_t)gy * IMG_W + 4 * q);
            // dest idx 2+4q -> byte 8 mod 16: write as two float2 (8B-aligned)
            *(float2*)&lds[0][lr][2 + 4 * q] = make_float2(pv.x, pv.y);
            *(float2*)&lds[0][lr][4 + 4 * q] = make_float2(pv.z, pv.w);
            *(float2*)&lds[1][lr][2 + 4 * q] = make_float2(gv.x, gv.y);
            *(float2*)&lds[1][lr][4 + 4 * q] = make_float2(gv.z, gv.w);
        }
    }

    // ---- bake horizontal reflect halo (96 scalar loads, hit L2) ----
    // window col -2 -> col 2 (idx 0), -1 -> 1 (idx 1), 512 -> 510 (idx 514),
    // 513 -> 509 (idx 515).
    if (threadIdx.x < 96) {
        const int r = threadIdx.x >> 3;         // 0..11
        const int i = (threadIdx.x >> 2) & 1;   // input
        const int c = threadIdx.x & 3;          // halo slot
        const int srccol = (c == 0) ? 2 : (c == 1) ? 1 : (c == 2) ? 510 : 509;
        const int dst    = (c == 0) ? 0 : (c == 1) ? 1 : (c == 2) ? 514 : 515;
        const int gy = reflect_b(h0 - 2 + r);
        const float* base = i ? gimg : pimg;
        lds[i][r][dst] = base[(size_t)gy * IMG_W + srccol];
    }
    __syncthreads();

    // ---- compute: thread = 4 cols x 4 rows ----
    const int sc  = threadIdx.x & 127;      // col quad (consecutive lanes)
    const int sl  = threadIdx.x >> 7;       // row half (0/1)
    const int c4  = 4 * sc;                 // window start idx in LDS row
    const int sl4 = 4 * sl;                 // first window row in LDS

    float pw[8][8], gw[8][8];
    int c0 = 0, c1 = 0, c2 = 0, c3 = 0;

    ROW_LD(0) ROW_LD(1) ROW_LD(2) ROW_LD(3) ROW_LD(4)
    DO_ROW(0)
    ROW_LD(5) DO_ROW(1)
    ROW_LD(6) DO_ROW(2)
    ROW_LD(7) DO_ROW(3)

    int cnt = (c0 + c1) + (c2 + c3);

    // ---- exact integer reduction (block-local; NO global atomics) ----
    #pragma unroll
    for (int off = 32; off > 0; off >>= 1)
        cnt += __shfl_down(cnt, off, 64);

    __shared__ int wave_sums[BLOCK / 64];
    const int lane = threadIdx.x & 63;
    const int wid  = threadIdx.x >> 6;
    if (lane == 0) wave_sums[wid] = cnt;
    __syncthreads();

    if (threadIdx.x == 0) {
        // One plain store per block to a distinct address: zero contention,
        // no fence, no readback. Wave retires immediately.
        ws[blockIdx.x] = (unsigned int)(wave_sums[0] + wave_sums[1] +
                                        wave_sums[2] + wave_sums[3]);
    }
}

// Second pass: one block sums the 1536 per-block partials and writes the mean.
// Kernel-boundary release/acquire makes census_main's stores visible here.
__global__ __launch_bounds__(BLOCK, 1) void census_reduce(
    const unsigned int* __restrict__ ws, float* __restrict__ out)
{
    unsigned int s = 0;
    #pragma unroll
    for (int i = 0; i < NBLOCKS / BLOCK; ++i)      // 6 iterations
        s += ws[threadIdx.x + i * BLOCK];

    #pragma unroll
    for (int off = 32; off > 0; off >>= 1)
        s += __shfl_down(s, off, 64);

    __shared__ unsigned int wsum[BLOCK / 64];
    const int lane = threadIdx.x & 63;
    const int wid  = threadIdx.x >> 6;
    if (lane == 0) wsum[wid] = s;
    __syncthreads();

    if (threadIdx.x == 0) {
        unsigned int tot = wsum[0] + wsum[1] + wsum[2] + wsum[3];
        out[0] = (float)((double)tot / (double)NPIX);
    }
}

extern "C" void kernel_launch(void* const* d_in, const int* in_sizes, int n_in,
                              void* d_out, int out_size, void* d_ws, size_t ws_size,
                              hipStream_t stream) {
    const float* pred = (const float*)d_in[0];
    const float* gt   = (const float*)d_in[1];
    float* out        = (float*)d_out;
    unsigned int* ws  = (unsigned int*)d_ws;   // needs NBLOCKS*4 = 6144 B

    census_main<<<NBLOCKS, BLOCK, 0, stream>>>(pred, gt, ws);
    census_reduce<<<1, BLOCK, 0, stream>>>(ws, out);
}